// Round 1
// baseline (64.202 us; speedup 1.0000x reference)
//
#include <hip/hip_runtime.h>

#define N_NEUR 4096
#define T_STEPS 2048
#define DT 0.001f
#define TAU 10.0f
#define V_TH 100.0f
#define V_R -100.0f
#define DECAY (1.0f - DT / TAU)   // 0.9999f

// ---------------------------------------------------------------------------
// K0: zero the spike flag (lives in d_ws; d_ws is poisoned, never re-zeroed)
// ---------------------------------------------------------------------------
__global__ void k_init_flag(int* flag) {
    if (threadIdx.x == 0 && blockIdx.x == 0) *flag = 0;
}

// ---------------------------------------------------------------------------
// K1: speculative per-neuron u-scan (valid until first global spike, which it
// detects). Blocks 0..63: one thread per neuron, scan all T steps assuming
// s_i = s0_i * DECAY^t (exact while no spikes anywhere). Blocks 64+: stream x
// to warm L3 so the latency-bound scan loads hit cache.
// ---------------------------------------------------------------------------
__global__ __launch_bounds__(64) void k_scan(const float* __restrict__ x,
                                             const float* __restrict__ u0,
                                             const float* __restrict__ s0,
                                             int* __restrict__ flag) {
    const int b = blockIdx.x;
    if (b < 64) {
        const int i = b * 64 + (int)threadIdx.x;
        float u = u0[i];
        float s = s0[i];
        float umax = u;                 // u_t is checked BEFORE each update
        const float* xp = x + i;
        #pragma unroll 1
        for (int t0 = 0; t0 < T_STEPS; t0 += 32) {
            float a[32];
            float ss = s;
            #pragma unroll
            for (int k = 0; k < 32; ++k) {   // 32 loads in flight (MLP)
                a[k] = xp[(size_t)(t0 + k) * N_NEUR] + ss;
                ss *= DECAY;
            }
            s = ss;
            #pragma unroll
            for (int k = 0; k < 32; ++k) {   // dependent chain: 2 FMAs/step
                umax = fmaxf(umax, u);
                u = fmaf(DT, fmaf(u, u, a[k]), u);
            }
        }
        if (umax >= V_TH) atomicOr(flag, 1);
    } else {
        // L3 warmer: stream x ahead of the scan, row-order
        const float4* xv = (const float4*)x;
        const int total = T_STEPS * N_NEUR / 4;
        const int nw = ((int)gridDim.x - 64) * 64;
        int wid = (b - 64) * 64 + (int)threadIdx.x;
        float acc = 0.f;
        for (int m = wid; m < total; m += nw) {
            float4 v = xv[m];
            acc += v.x + v.y + v.z + v.w;
        }
        asm volatile("" :: "v"(acc));   // keep loads alive
    }
}

// ---------------------------------------------------------------------------
// K2: fast-path writer. If no spike anywhere, s_trace[t] = s0 * DECAY^(t+1)
// (exact zeros for s0 == 0). One block per row t, coalesced float4 stores.
// ---------------------------------------------------------------------------
__global__ __launch_bounds__(256) void k_write_decay(const float* __restrict__ s0,
                                                     float* __restrict__ out,
                                                     const int* __restrict__ flag) {
    if (*flag) return;
    const int t = blockIdx.x;
    const float scale = __powf(DECAY, (float)(t + 1));
    const float4* s4 = (const float4*)s0;
    float4* o4 = (float4*)out + (size_t)t * (N_NEUR / 4);
    #pragma unroll
    for (int p = 0; p < 4; ++p) {
        const int c = p * 256 + (int)threadIdx.x;
        float4 v = s4[c];
        v.x *= scale; v.y *= scale; v.z *= scale; v.w *= scale;
        o4[c] = v;
    }
}

// ---------------------------------------------------------------------------
// K3: fully-general sequential fallback (single block -> __syncthreads per
// step, no cooperative-launch / cross-XCD coherence risk). Sparse event-driven
// matvec via spike list. Early-exits when flag == 0 (the expected case).
// ---------------------------------------------------------------------------
__global__ __launch_bounds__(1024) void k_slow(const float* __restrict__ x,
                                               const float* __restrict__ W,
                                               const float* __restrict__ u0,
                                               const float* __restrict__ s0,
                                               float* __restrict__ out,
                                               const int* __restrict__ flag) {
    if (*flag == 0) return;
    __shared__ float u[N_NEUR];
    __shared__ float s[N_NEUR];
    __shared__ int list[N_NEUR];
    __shared__ int cnt;
    const int tid = (int)threadIdx.x;
    for (int m = tid; m < N_NEUR; m += 1024) { u[m] = u0[m]; s[m] = s0[m]; }
    if (tid == 0) cnt = 0;
    __syncthreads();
    for (int t = 0; t < T_STEPS; ++t) {
        // phase 1: spikes from u_old; u update uses OLD s; reset with old mask
        #pragma unroll
        for (int q = 0; q < 4; ++q) {
            const int i = tid + q * 1024;
            const float ui = u[i];
            const bool spk = ui >= V_TH;
            float un = ui + DT * (ui * ui + x[(size_t)t * N_NEUR + i] + s[i]);
            if (spk) {
                int p = atomicAdd(&cnt, 1);
                list[p] = i;
                un = V_R;
            }
            u[i] = un;
        }
        __syncthreads();
        const int k = cnt;
        // phase 2: s_new = s*(1-dt/tau) + sum over spiking columns of W
        #pragma unroll
        for (int q = 0; q < 4; ++q) {
            const int i = tid + q * 1024;
            float acc = 0.f;
            for (int m = 0; m < k; ++m) acc += W[(size_t)i * N_NEUR + list[m]];
            const float sn = s[i] * DECAY + acc;
            s[i] = sn;
            out[(size_t)t * N_NEUR + i] = sn;
        }
        __syncthreads();
        if (tid == 0) cnt = 0;
        __syncthreads();
    }
}

// ---------------------------------------------------------------------------
extern "C" void kernel_launch(void* const* d_in, const int* in_sizes, int n_in,
                              void* d_out, int out_size, void* d_ws, size_t ws_size,
                              hipStream_t stream) {
    const float* x  = (const float*)d_in[0];   // [T, N]
    const float* W  = (const float*)d_in[1];   // [N, N]
    const float* u0 = (const float*)d_in[2];   // [N]
    const float* s0 = (const float*)d_in[3];   // [N]
    float* out = (float*)d_out;                // [T, N]
    int* flag = (int*)d_ws;

    k_init_flag<<<1, 64, 0, stream>>>(flag);
    k_scan<<<512, 64, 0, stream>>>(x, u0, s0, flag);
    k_write_decay<<<T_STEPS, 256, 0, stream>>>(s0, out, flag);
    k_slow<<<1, 1024, 0, stream>>>(x, W, u0, s0, out, flag);
}